// Round 3
// baseline (1039.422 us; speedup 1.0000x reference)
//
#include <hip/hip_runtime.h>

#define NN 50000
#define NE 800000
#define EP (NE + NN)      // edges + self loops (= 850000, divisible by 16)
#define HID 128
#define FIN 64
#define NG 64
#define SLOPE 0.2f
#define STRIP 16          // edges per wave in k_spmv

__device__ __forceinline__ float wred_sum(float v) {
  for (int off = 32; off; off >>= 1) v += __shfl_xor(v, off);
  return v;
}
__device__ __forceinline__ float wred_max(float v) {
  for (int off = 32; off; off >>= 1) v = fmaxf(v, __shfl_xor(v, off));
  return v;
}

// ---- mean of edge weights -------------------------------------------------
__global__ void k_mean(const float* __restrict__ ew, float* __restrict__ meansum) {
  int tid = blockIdx.x * blockDim.x + threadIdx.x;
  int stride = gridDim.x * blockDim.x;
  float s = 0.f;
  for (int i = tid; i < NE; i += stride) s += ew[i];
  s = wred_sum(s);
  if ((threadIdx.x & 63) == 0) atomicAdd(meansum, s);
}

// ---- histogram of destinations (incl self loops) --------------------------
__global__ void k_hist(const int* __restrict__ edst, int* __restrict__ counts) {
  int tid = blockIdx.x * blockDim.x + threadIdx.x;
  int stride = gridDim.x * blockDim.x;
  for (int i = tid; i < EP; i += stride) {
    int d = (i < NE) ? edst[i] : (i - NE);
    atomicAdd(&counts[d], 1);
  }
}

// ---- single-block exclusive scan; also zeroes counts (reused as cursor) ---
__global__ void k_scan(int* __restrict__ counts, int* __restrict__ starts) {
  __shared__ int wsum[16];
  __shared__ int woff[16];
  int t = threadIdx.x;
  int lane = t & 63;
  int w = t >> 6;
  int carry = 0;
  for (int base = 0; base < NN; base += 1024) {
    int i = base + t;
    int v = (i < NN) ? counts[i] : 0;
    if (i < NN) counts[i] = 0;   // reset cursor for scatter
    int sc = v;
    #pragma unroll
    for (int d = 1; d < 64; d <<= 1) {
      int u = __shfl_up(sc, d);
      if (lane >= d) sc += u;
    }
    if (lane == 63) wsum[w] = sc;
    __syncthreads();
    if (w == 0 && lane < 16) {
      int x = wsum[lane];
      #pragma unroll
      for (int d = 1; d < 16; d <<= 1) {
        int u = __shfl_up(x, d);
        if (lane >= d) x += u;
      }
      woff[lane] = x;   // inclusive scan of wave sums
    }
    __syncthreads();
    int waveoff = (w == 0) ? 0 : woff[w - 1];
    if (i < NN) starts[i] = carry + waveoff + sc - v;
    carry += woff[15];
    __syncthreads();   // protect wsum/woff before next chunk
  }
  if (t == 0) starts[NN] = carry;
}

// ---- scatter edges into dst-sorted order ----------------------------------
__global__ void k_scatter(const int* __restrict__ esrc, const int* __restrict__ edst,
                          const float* __restrict__ ew, const float* __restrict__ meansum,
                          const int* __restrict__ starts, int* __restrict__ cursor,
                          int* __restrict__ srcs, int* __restrict__ dsts,
                          float* __restrict__ wgts) {
  float mw = meansum[0] * (1.0f / NE);
  int tid = blockIdx.x * blockDim.x + threadIdx.x;
  int stride = gridDim.x * blockDim.x;
  for (int i = tid; i < EP; i += stride) {
    int s, d; float wv;
    if (i < NE) { s = esrc[i]; d = edst[i]; wv = ew[i]; }
    else        { s = d = i - NE; wv = mw; }
    int pos = starts[d] + atomicAdd(&cursor[d], 1);
    srcs[pos] = s; dsts[pos] = d; wgts[pos] = wv;
  }
}

// ---- fp32 GEMM: C[n x 128] = A[n x K] @ W[K x 128] + b --------------------
template <int K>
__global__ __launch_bounds__(256) void k_gemm(const float* __restrict__ A,
                                              const float* __restrict__ W,
                                              const float* __restrict__ b,
                                              float* __restrict__ C, int n) {
  __shared__ float As[64][K];
  int t = threadIdx.x;
  int nb = blockIdx.x * 64;
  constexpr int F4 = 16 * K;     // float4 count in the A tile
  for (int i = t; i < F4; i += 256) {
    int row = i / (K / 4);
    int c = (i % (K / 4)) * 4;
    int gn = nb + row;
    float4 v = make_float4(0.f, 0.f, 0.f, 0.f);
    if (gn < n) v = *(const float4*)(A + (size_t)gn * K + c);
    *(float4*)&As[row][c] = v;
  }
  __syncthreads();
  int fx = (t & 31) * 4;
  int ny = (t >> 5) * 8;
  float acc[8][4] = {};
  for (int k = 0; k < K; ++k) {
    float4 wv = *(const float4*)(W + (size_t)k * HID + fx);
    #pragma unroll
    for (int j = 0; j < 8; ++j) {
      float a = As[ny + j][k];
      acc[j][0] += a * wv.x; acc[j][1] += a * wv.y;
      acc[j][2] += a * wv.z; acc[j][3] += a * wv.w;
    }
  }
  float4 bb = *(const float4*)(b + fx);
  #pragma unroll
  for (int j = 0; j < 8; ++j) {
    int gn = nb + ny + j;
    if (gn < n) {
      float4 o = make_float4(acc[j][0] + bb.x, acc[j][1] + bb.y,
                             acc[j][2] + bb.z, acc[j][3] + bb.w);
      *(float4*)(C + (size_t)gn * HID + fx) = o;
    }
  }
}

// ---- per-edge attention logits (wave per edge) ----------------------------
__global__ void k_logits(const float* __restrict__ xl, const float* __restrict__ xr,
                         const int* __restrict__ srcs, const int* __restrict__ dsts,
                         const float* __restrict__ wgts, const float* __restrict__ We,
                         const float* __restrict__ att, float* __restrict__ logits) {
  int gtid = blockIdx.x * blockDim.x + threadIdx.x;
  int wave = gtid >> 6;
  int lane = gtid & 63;
  int nw = (gridDim.x * blockDim.x) >> 6;
  int f = lane * 2;
  float we0 = We[f], we1 = We[f + 1];
  float at0 = att[f], at1 = att[f + 1];
  for (int p = wave; p < EP; p += nw) {
    int s = srcs[p], d = dsts[p];
    float wv = wgts[p];
    float2 a = *(const float2*)(xl + (size_t)s * HID + f);
    float2 b = *(const float2*)(xr + (size_t)d * HID + f);
    float v0 = a.x + b.x + wv * we0;
    float v1 = a.y + b.y + wv * we1;
    v0 = v0 > 0.f ? v0 : SLOPE * v0;
    v1 = v1 > 0.f ? v1 : SLOPE * v1;
    float part = wred_sum(v0 * at0 + v1 * at1);
    if (lane == 0) logits[p] = part;
  }
}

// ---- per-node softmax: logits -> alpha (in place) --------------------------
// Each wave owns one node's CSR range exclusively; 3 passes over its logits
// (deg <= 64 -> one iteration each, L1-hot).
__global__ void k_stats(float* __restrict__ logits, const int* __restrict__ starts) {
  int node = blockIdx.x * (blockDim.x >> 6) + (threadIdx.x >> 6);
  int lane = threadIdx.x & 63;
  if (node >= NN) return;
  int s0 = starts[node], s1 = starts[node + 1];
  float m = -1e30f;
  for (int i = s0 + lane; i < s1; i += 64) m = fmaxf(m, logits[i]);
  m = wred_max(m);
  float ssum = 0.f;
  for (int i = s0 + lane; i < s1; i += 64) ssum += __expf(logits[i] - m);
  ssum = wred_sum(ssum);
  float inv = 1.0f / ssum;
  for (int i = s0 + lane; i < s1; i += 64) logits[i] = __expf(logits[i] - m) * inv;
}

// ---- edge-parallel weighted aggregation -----------------------------------
// Wave handles STRIP consecutive dst-sorted edges: all STRIP row-gathers are
// issued up-front into registers (one latency for the whole strip), then the
// run-detected partial sums are flushed with atomics onto a zeroed buffer.
__global__ __launch_bounds__(256) void k_spmv(const float* __restrict__ xl,
                                              const int* __restrict__ srcs,
                                              const int* __restrict__ dsts,
                                              const float* __restrict__ alpha,
                                              float* __restrict__ out) {
  int wid = (blockIdx.x * blockDim.x + threadIdx.x) >> 6;
  int lane = threadIdx.x & 63;
  int e0 = wid * STRIP;
  if (e0 >= EP) return;
  int f = lane * 2;
  int idx = e0 + (lane & (STRIP - 1));
  int s = srcs[idx];
  int d = dsts[idx];
  float a = alpha[idx];
  float2 v[STRIP];
  #pragma unroll
  for (int j = 0; j < STRIP; ++j) {
    int sj = __shfl(s, j);
    v[j] = *(const float2*)(xl + (size_t)sj * HID + f);
  }
  float2 acc = make_float2(0.f, 0.f);
  int dprev = __shfl(d, 0);
  #pragma unroll
  for (int j = 0; j < STRIP; ++j) {
    int dj = __shfl(d, j);
    float aj = __shfl(a, j);
    if (dj != dprev) {
      atomicAdd(&out[(size_t)dprev * HID + f], acc.x);
      atomicAdd(&out[(size_t)dprev * HID + f + 1], acc.y);
      acc.x = 0.f; acc.y = 0.f;
      dprev = dj;
    }
    acc.x += aj * v[j].x;
    acc.y += aj * v[j].y;
  }
  atomicAdd(&out[(size_t)dprev * HID + f], acc.x);
  atomicAdd(&out[(size_t)dprev * HID + f + 1], acc.y);
}

// ---- bias + relu (+ optional pooling) -------------------------------------
// PHASE 0: h = relu(agg + bias) in place. PHASE 1: pool relu(agg+bias) into
// per-graph sums.
template <int PHASE>
__global__ void k_bias(float* __restrict__ agg, const float* __restrict__ bias,
                       const int* __restrict__ batch, float* __restrict__ pool_sums,
                       float* __restrict__ pool_cnt) {
  int node = blockIdx.x * (blockDim.x >> 6) + (threadIdx.x >> 6);
  int lane = threadIdx.x & 63;
  if (node >= NN) return;
  int f = lane * 2;
  float2 v = *(const float2*)(agg + (size_t)node * HID + f);
  v.x = fmaxf(v.x + bias[f], 0.f);
  v.y = fmaxf(v.y + bias[f + 1], 0.f);
  if (PHASE == 0) {
    *(float2*)(agg + (size_t)node * HID + f) = v;
  } else {
    int g = batch[node];
    atomicAdd(&pool_sums[g * HID + f], v.x);
    atomicAdd(&pool_sums[g * HID + f + 1], v.y);
    if (lane == 0) atomicAdd(&pool_cnt[g], 1.f);
  }
}

// ---- pooled @ Wlin + blin -------------------------------------------------
__global__ void k_final(const float* __restrict__ pool_sums, const float* __restrict__ pool_cnt,
                        const float* __restrict__ Wlin, const float* __restrict__ blin,
                        float* __restrict__ out) {
  int wid = (blockIdx.x * blockDim.x + threadIdx.x) >> 6;
  int lane = threadIdx.x & 63;
  if (wid >= NG) return;
  int f = lane * 2;
  float2 s = *(const float2*)(pool_sums + (size_t)wid * HID + f);
  float part = s.x * Wlin[f] + s.y * Wlin[f + 1];
  part = wred_sum(part);
  if (lane == 0) {
    float cnt = fmaxf(pool_cnt[wid], 1.f);
    out[wid] = part / cnt + blin[0];
  }
}

extern "C" void kernel_launch(void* const* d_in, const int* in_sizes, int n_in,
                              void* d_out, int out_size, void* d_ws, size_t ws_size,
                              hipStream_t stream) {
  const float* x     = (const float*)d_in[0];
  const int*   ei    = (const int*)d_in[1];      // [2][NE]
  const float* ew    = (const float*)d_in[2];
  const int*   batch = (const int*)d_in[3];
  const float* W1l = (const float*)d_in[4];
  const float* b1l = (const float*)d_in[5];
  const float* W1r = (const float*)d_in[6];
  const float* b1r = (const float*)d_in[7];
  const float* We1 = (const float*)d_in[8];
  const float* at1 = (const float*)d_in[9];
  const float* bi1 = (const float*)d_in[10];
  const float* W2l = (const float*)d_in[11];
  const float* b2l = (const float*)d_in[12];
  const float* W2r = (const float*)d_in[13];
  const float* b2r = (const float*)d_in[14];
  const float* We2 = (const float*)d_in[15];
  const float* at2 = (const float*)d_in[16];
  const float* bi2 = (const float*)d_in[17];
  const float* Wlin = (const float*)d_in[18];
  const float* blin = (const float*)d_in[19];

  float* ws = (float*)d_ws;
  size_t o = 0;
  float* xl     = ws + o; o += (size_t)NN * HID;
  float* xr     = ws + o; o += (size_t)NN * HID;
  float* hb     = ws + o; o += (size_t)NN * HID;
  float* logits = ws + o; o += EP;            // becomes alpha in place
  float* wgts   = ws + o; o += EP;
  int*   srcs   = (int*)(ws + o); o += EP;
  int*   dsts   = (int*)(ws + o); o += EP;
  int*   starts = (int*)(ws + o); o += NN + 1;
  size_t zoff = o;
  int*   counts    = (int*)(ws + o); o += NN;
  float* meansum   = ws + o; o += 1;
  float* pool_sums = ws + o; o += (size_t)NG * HID;
  float* pool_cnt  = ws + o; o += NG;
  size_t zero_bytes = (o - zoff) * sizeof(float);

  hipMemsetAsync(counts, 0, zero_bytes, stream);

  // build dst-sorted CSR (shared by both layers)
  k_mean<<<256, 256, 0, stream>>>(ew, meansum);
  k_hist<<<1024, 256, 0, stream>>>(ei + NE, counts);
  k_scan<<<1, 1024, 0, stream>>>(counts, starts);
  k_scatter<<<1024, 256, 0, stream>>>(ei, ei + NE, ew, meansum, starts, counts,
                                      srcs, dsts, wgts);

  int gb  = (NN + 63) / 64;                       // gemm blocks
  int nbn = (NN + 3) / 4;                         // node-per-wave blocks
  int sbn = ((EP / STRIP) + 3) / 4;               // spmv blocks
  size_t hbytes = (size_t)NN * HID * sizeof(float);

  // layer 1
  k_gemm<FIN><<<gb, 256, 0, stream>>>(x, W1l, b1l, xl, NN);
  k_gemm<FIN><<<gb, 256, 0, stream>>>(x, W1r, b1r, xr, NN);
  k_logits<<<4096, 256, 0, stream>>>(xl, xr, srcs, dsts, wgts, We1, at1, logits);
  k_stats<<<nbn, 256, 0, stream>>>(logits, starts);
  hipMemsetAsync(hb, 0, hbytes, stream);
  k_spmv<<<sbn, 256, 0, stream>>>(xl, srcs, dsts, logits, hb);
  k_bias<0><<<nbn, 256, 0, stream>>>(hb, bi1, nullptr, nullptr, nullptr);
  // layer 2
  k_gemm<HID><<<gb, 256, 0, stream>>>(hb, W2l, b2l, xl, NN);
  k_gemm<HID><<<gb, 256, 0, stream>>>(hb, W2r, b2r, xr, NN);
  k_logits<<<4096, 256, 0, stream>>>(xl, xr, srcs, dsts, wgts, We2, at2, logits);
  k_stats<<<nbn, 256, 0, stream>>>(logits, starts);
  hipMemsetAsync(hb, 0, hbytes, stream);          // hb already consumed by gemm2
  k_spmv<<<sbn, 256, 0, stream>>>(xl, srcs, dsts, logits, hb);
  k_bias<1><<<nbn, 256, 0, stream>>>(hb, bi2, batch, pool_sums, pool_cnt);
  // head
  k_final<<<16, 256, 0, stream>>>(pool_sums, pool_cnt, Wlin, blin, (float*)d_out);
}

// Round 4
// 725.800 us; speedup vs baseline: 1.4321x; 1.4321x over previous
//
#include <hip/hip_runtime.h>

#define NN 50000
#define NE 800000
#define EP (NE + NN)      // edges + self loops (= 850000)
#define HID 128
#define FIN 64
#define NG 64
#define SLOPE 0.2f
#define STRIP 32          // edges per wave in k_spmv

__device__ __forceinline__ float wred_sum(float v) {
  for (int off = 32; off; off >>= 1) v += __shfl_xor(v, off);
  return v;
}
__device__ __forceinline__ float wred_max(float v) {
  for (int off = 32; off; off >>= 1) v = fmaxf(v, __shfl_xor(v, off));
  return v;
}

// ---- mean of edge weights -------------------------------------------------
__global__ void k_mean(const float* __restrict__ ew, float* __restrict__ meansum) {
  int tid = blockIdx.x * blockDim.x + threadIdx.x;
  int stride = gridDim.x * blockDim.x;
  float s = 0.f;
  for (int i = tid; i < NE; i += stride) s += ew[i];
  s = wred_sum(s);
  if ((threadIdx.x & 63) == 0) atomicAdd(meansum, s);
}

// ---- histogram of destinations (incl self loops) --------------------------
__global__ void k_hist(const int* __restrict__ edst, int* __restrict__ counts) {
  int tid = blockIdx.x * blockDim.x + threadIdx.x;
  int stride = gridDim.x * blockDim.x;
  for (int i = tid; i < EP; i += stride) {
    int d = (i < NE) ? edst[i] : (i - NE);
    atomicAdd(&counts[d], 1);
  }
}

// ---- single-block exclusive scan; also zeroes counts (reused as cursor) ---
__global__ void k_scan(int* __restrict__ counts, int* __restrict__ starts) {
  __shared__ int wsum[16];
  __shared__ int woff[16];
  int t = threadIdx.x;
  int lane = t & 63;
  int w = t >> 6;
  int carry = 0;
  for (int base = 0; base < NN; base += 1024) {
    int i = base + t;
    int v = (i < NN) ? counts[i] : 0;
    if (i < NN) counts[i] = 0;   // reset cursor for scatter
    int sc = v;
    #pragma unroll
    for (int d = 1; d < 64; d <<= 1) {
      int u = __shfl_up(sc, d);
      if (lane >= d) sc += u;
    }
    if (lane == 63) wsum[w] = sc;
    __syncthreads();
    if (w == 0 && lane < 16) {
      int x = wsum[lane];
      #pragma unroll
      for (int d = 1; d < 16; d <<= 1) {
        int u = __shfl_up(x, d);
        if (lane >= d) x += u;
      }
      woff[lane] = x;   // inclusive scan of wave sums
    }
    __syncthreads();
    int waveoff = (w == 0) ? 0 : woff[w - 1];
    if (i < NN) starts[i] = carry + waveoff + sc - v;
    carry += woff[15];
    __syncthreads();   // protect wsum/woff before next chunk
  }
  if (t == 0) starts[NN] = carry;
}

// ---- scatter edges into dst-sorted order ----------------------------------
__global__ void k_scatter(const int* __restrict__ esrc, const int* __restrict__ edst,
                          const float* __restrict__ ew, const float* __restrict__ meansum,
                          const int* __restrict__ starts, int* __restrict__ cursor,
                          int* __restrict__ srcs, int* __restrict__ dsts,
                          float* __restrict__ wgts) {
  float mw = meansum[0] * (1.0f / NE);
  int tid = blockIdx.x * blockDim.x + threadIdx.x;
  int stride = gridDim.x * blockDim.x;
  for (int i = tid; i < EP; i += stride) {
    int s, d; float wv;
    if (i < NE) { s = esrc[i]; d = edst[i]; wv = ew[i]; }
    else        { s = d = i - NE; wv = mw; }
    int pos = starts[d] + atomicAdd(&cursor[d], 1);
    srcs[pos] = s; dsts[pos] = d; wgts[pos] = wv;
  }
}

// ---- fp32 GEMM: C[n x 128] = A[n x K] @ W[K x 128] + b --------------------
template <int K>
__global__ __launch_bounds__(256) void k_gemm(const float* __restrict__ A,
                                              const float* __restrict__ W,
                                              const float* __restrict__ b,
                                              float* __restrict__ C, int n) {
  __shared__ float As[64][K];
  int t = threadIdx.x;
  int nb = blockIdx.x * 64;
  constexpr int F4 = 16 * K;     // float4 count in the A tile
  for (int i = t; i < F4; i += 256) {
    int row = i / (K / 4);
    int c = (i % (K / 4)) * 4;
    int gn = nb + row;
    float4 v = make_float4(0.f, 0.f, 0.f, 0.f);
    if (gn < n) v = *(const float4*)(A + (size_t)gn * K + c);
    *(float4*)&As[row][c] = v;
  }
  __syncthreads();
  int fx = (t & 31) * 4;
  int ny = (t >> 5) * 8;
  float acc[8][4] = {};
  for (int k = 0; k < K; ++k) {
    float4 wv = *(const float4*)(W + (size_t)k * HID + fx);
    #pragma unroll
    for (int j = 0; j < 8; ++j) {
      float a = As[ny + j][k];
      acc[j][0] += a * wv.x; acc[j][1] += a * wv.y;
      acc[j][2] += a * wv.z; acc[j][3] += a * wv.w;
    }
  }
  float4 bb = *(const float4*)(b + fx);
  #pragma unroll
  for (int j = 0; j < 8; ++j) {
    int gn = nb + ny + j;
    if (gn < n) {
      float4 o = make_float4(acc[j][0] + bb.x, acc[j][1] + bb.y,
                             acc[j][2] + bb.z, acc[j][3] + bb.w);
      *(float4*)(C + (size_t)gn * HID + fx) = o;
    }
  }
}

// ---- per-edge attention logits (wave per edge) ----------------------------
__global__ void k_logits(const float* __restrict__ xl, const float* __restrict__ xr,
                         const int* __restrict__ srcs, const int* __restrict__ dsts,
                         const float* __restrict__ wgts, const float* __restrict__ We,
                         const float* __restrict__ att, float* __restrict__ logits) {
  int gtid = blockIdx.x * blockDim.x + threadIdx.x;
  int wave = gtid >> 6;
  int lane = gtid & 63;
  int nw = (gridDim.x * blockDim.x) >> 6;
  int f = lane * 2;
  float we0 = We[f], we1 = We[f + 1];
  float at0 = att[f], at1 = att[f + 1];
  for (int p = wave; p < EP; p += nw) {
    int s = srcs[p], d = dsts[p];
    float wv = wgts[p];
    float2 a = *(const float2*)(xl + (size_t)s * HID + f);
    float2 b = *(const float2*)(xr + (size_t)d * HID + f);
    float v0 = a.x + b.x + wv * we0;
    float v1 = a.y + b.y + wv * we1;
    v0 = v0 > 0.f ? v0 : SLOPE * v0;
    v1 = v1 > 0.f ? v1 : SLOPE * v1;
    float part = wred_sum(v0 * at0 + v1 * at1);
    if (lane == 0) logits[p] = part;
  }
}

// ---- per-node softmax: logits -> alpha (in place) --------------------------
__global__ void k_stats(float* __restrict__ logits, const int* __restrict__ starts) {
  int node = blockIdx.x * (blockDim.x >> 6) + (threadIdx.x >> 6);
  int lane = threadIdx.x & 63;
  if (node >= NN) return;
  int s0 = starts[node], s1 = starts[node + 1];
  float m = -1e30f;
  for (int i = s0 + lane; i < s1; i += 64) m = fmaxf(m, logits[i]);
  m = wred_max(m);
  float ssum = 0.f;
  for (int i = s0 + lane; i < s1; i += 64) ssum += __expf(logits[i] - m);
  ssum = wred_sum(ssum);
  float inv = 1.0f / ssum;
  for (int i = s0 + lane; i < s1; i += 64) logits[i] = __expf(logits[i] - m) * inv;
}

// ---- edge-parallel weighted aggregation (wave per 32-edge strip) ----------
__global__ __launch_bounds__(256) void k_spmv(const float* __restrict__ xl,
                                              const int* __restrict__ srcs,
                                              const int* __restrict__ dsts,
                                              const float* __restrict__ alpha,
                                              float* __restrict__ out) {
  int wid = (blockIdx.x * blockDim.x + threadIdx.x) >> 6;
  int lane = threadIdx.x & 63;
  int e0 = wid * STRIP;
  if (e0 >= EP) return;
  int f = lane * 2;
  int eid = e0 + (lane & (STRIP - 1));
  int idx = min(eid, EP - 1);
  int s = srcs[idx];
  int d = dsts[idx];
  float a = (eid < EP) ? alpha[idx] : 0.f;
  float2 v[STRIP];
  #pragma unroll
  for (int j = 0; j < STRIP; ++j) {
    int sj = __shfl(s, j);
    v[j] = *(const float2*)(xl + (size_t)sj * HID + f);
  }
  float2 acc = make_float2(0.f, 0.f);
  int dprev = __shfl(d, 0);
  #pragma unroll
  for (int j = 0; j < STRIP; ++j) {
    int dj = __shfl(d, j);
    float aj = __shfl(a, j);
    if (dj != dprev) {
      atomicAdd(&out[(size_t)dprev * HID + f], acc.x);
      atomicAdd(&out[(size_t)dprev * HID + f + 1], acc.y);
      acc.x = 0.f; acc.y = 0.f;
      dprev = dj;
    }
    acc.x += aj * v[j].x;
    acc.y += aj * v[j].y;
  }
  atomicAdd(&out[(size_t)dprev * HID + f], acc.x);
  atomicAdd(&out[(size_t)dprev * HID + f + 1], acc.y);
}

// ---- bias + relu in place ---------------------------------------------------
__global__ void k_bias(float* __restrict__ agg, const float* __restrict__ bias) {
  int node = blockIdx.x * (blockDim.x >> 6) + (threadIdx.x >> 6);
  int lane = threadIdx.x & 63;
  if (node >= NN) return;
  int f = lane * 2;
  float2 v = *(const float2*)(agg + (size_t)node * HID + f);
  v.x = fmaxf(v.x + bias[f], 0.f);
  v.y = fmaxf(v.y + bias[f + 1], 0.f);
  *(float2*)(agg + (size_t)node * HID + f) = v;
}

// ---- graph boundaries from sorted batch ------------------------------------
__global__ void k_bounds(const int* __restrict__ batch, int* __restrict__ gs) {
  int i = blockIdx.x * blockDim.x + threadIdx.x;
  if (i >= NN) return;
  int b = batch[i];
  if (i == 0) {
    for (int g = 0; g <= b; ++g) gs[g] = 0;
  }
  int bn = (i + 1 < NN) ? batch[i + 1] : NG;
  for (int g = b + 1; g <= bn; ++g) gs[g] = i + 1;
}

// ---- segmented mean pool + final linear (one block per graph) --------------
__global__ __launch_bounds__(256) void k_pool(const float* __restrict__ h,
                                              const int* __restrict__ gs,
                                              const float* __restrict__ Wlin,
                                              const float* __restrict__ blin,
                                              float* __restrict__ out) {
  __shared__ float red[256];
  int g = blockIdx.x;
  int t = threadIdx.x;
  int f = t & 127;
  int half = t >> 7;           // 0 or 1
  int n0 = gs[g], n1 = gs[g + 1];
  float s0 = 0.f, s1 = 0.f, s2 = 0.f, s3 = 0.f;
  int n = n0 + half;
  for (; n + 6 < n1; n += 8) {
    s0 += h[(size_t)n * HID + f];
    s1 += h[(size_t)(n + 2) * HID + f];
    s2 += h[(size_t)(n + 4) * HID + f];
    s3 += h[(size_t)(n + 6) * HID + f];
  }
  for (; n < n1; n += 2) s0 += h[(size_t)n * HID + f];
  red[t] = (s0 + s1) + (s2 + s3);
  __syncthreads();
  if (t < 128) {
    float pooled = red[t] + red[t + 128];
    float cnt = (float)max(n1 - n0, 1);
    red[t] = (pooled / cnt) * Wlin[f];
  }
  __syncthreads();
  if (t < 64) {
    float v = red[t] + red[t + 64];
    v = wred_sum(v);
    if (t == 0) out[g] = v + blin[0];
  }
}

extern "C" void kernel_launch(void* const* d_in, const int* in_sizes, int n_in,
                              void* d_out, int out_size, void* d_ws, size_t ws_size,
                              hipStream_t stream) {
  const float* x     = (const float*)d_in[0];
  const int*   ei    = (const int*)d_in[1];      // [2][NE]
  const float* ew    = (const float*)d_in[2];
  const int*   batch = (const int*)d_in[3];
  const float* W1l = (const float*)d_in[4];
  const float* b1l = (const float*)d_in[5];
  const float* W1r = (const float*)d_in[6];
  const float* b1r = (const float*)d_in[7];
  const float* We1 = (const float*)d_in[8];
  const float* at1 = (const float*)d_in[9];
  const float* bi1 = (const float*)d_in[10];
  const float* W2l = (const float*)d_in[11];
  const float* b2l = (const float*)d_in[12];
  const float* W2r = (const float*)d_in[13];
  const float* b2r = (const float*)d_in[14];
  const float* We2 = (const float*)d_in[15];
  const float* at2 = (const float*)d_in[16];
  const float* bi2 = (const float*)d_in[17];
  const float* Wlin = (const float*)d_in[18];
  const float* blin = (const float*)d_in[19];

  float* ws = (float*)d_ws;
  size_t o = 0;
  float* xl     = ws + o; o += (size_t)NN * HID;
  float* xr     = ws + o; o += (size_t)NN * HID;
  float* hb     = ws + o; o += (size_t)NN * HID;
  float* logits = ws + o; o += EP;            // becomes alpha in place
  float* wgts   = ws + o; o += EP;
  int*   srcs   = (int*)(ws + o); o += EP;
  int*   dsts   = (int*)(ws + o); o += EP;
  int*   starts = (int*)(ws + o); o += NN + 1;
  int*   gs     = (int*)(ws + o); o += NG + 1;
  size_t zoff = o;
  int*   counts    = (int*)(ws + o); o += NN;
  float* meansum   = ws + o; o += 1;
  size_t zero_bytes = (o - zoff) * sizeof(float);

  hipMemsetAsync(counts, 0, zero_bytes, stream);

  // build dst-sorted CSR (shared by both layers) + graph bounds
  k_mean<<<256, 256, 0, stream>>>(ew, meansum);
  k_hist<<<1024, 256, 0, stream>>>(ei + NE, counts);
  k_scan<<<1, 1024, 0, stream>>>(counts, starts);
  k_scatter<<<1024, 256, 0, stream>>>(ei, ei + NE, ew, meansum, starts, counts,
                                      srcs, dsts, wgts);
  k_bounds<<<(NN + 255) / 256, 256, 0, stream>>>(batch, gs);

  int gb  = (NN + 63) / 64;                       // gemm blocks
  int nbn = (NN + 3) / 4;                         // node-per-wave blocks
  int nstrips = (EP + STRIP - 1) / STRIP;
  int sbn = (nstrips + 3) / 4;                    // spmv blocks
  size_t hbytes = (size_t)NN * HID * sizeof(float);

  // layer 1
  k_gemm<FIN><<<gb, 256, 0, stream>>>(x, W1l, b1l, xl, NN);
  k_gemm<FIN><<<gb, 256, 0, stream>>>(x, W1r, b1r, xr, NN);
  k_logits<<<4096, 256, 0, stream>>>(xl, xr, srcs, dsts, wgts, We1, at1, logits);
  k_stats<<<nbn, 256, 0, stream>>>(logits, starts);
  hipMemsetAsync(hb, 0, hbytes, stream);
  k_spmv<<<sbn, 256, 0, stream>>>(xl, srcs, dsts, logits, hb);
  k_bias<<<nbn, 256, 0, stream>>>(hb, bi1);
  // layer 2
  k_gemm<HID><<<gb, 256, 0, stream>>>(hb, W2l, b2l, xl, NN);
  k_gemm<HID><<<gb, 256, 0, stream>>>(hb, W2r, b2r, xr, NN);
  k_logits<<<4096, 256, 0, stream>>>(xl, xr, srcs, dsts, wgts, We2, at2, logits);
  k_stats<<<nbn, 256, 0, stream>>>(logits, starts);
  hipMemsetAsync(hb, 0, hbytes, stream);          // hb already consumed by gemm2
  k_spmv<<<sbn, 256, 0, stream>>>(xl, srcs, dsts, logits, hb);
  k_bias<<<nbn, 256, 0, stream>>>(hb, bi2);
  // pool + head (no atomics: batch is sorted -> contiguous graph ranges)
  k_pool<<<NG, 256, 0, stream>>>(hb, gs, Wlin, blin, (float*)d_out);
}